// Round 8
// baseline (1019.246 us; speedup 1.0000x reference)
//
#include <hip/hip_runtime.h>
#include <math.h>

typedef unsigned short bfu;   // raw bf16 bits
typedef __attribute__((ext_vector_type(8))) short short8;
typedef __attribute__((ext_vector_type(4))) short sh4;
typedef __attribute__((ext_vector_type(4))) float floatx4;

__device__ __forceinline__ float bu2f(bfu u){
  return __builtin_bit_cast(float, (unsigned)u << 16);
}
__device__ __forceinline__ bfu f2bu(float f){
  unsigned x = __builtin_bit_cast(unsigned, f);
  unsigned r = (x + 0x7FFFu + ((x >> 16) & 1u)) >> 16;   // RNE
  return (bfu)r;
}
__device__ __forceinline__ void gld16(const bfu* g, bfu* l){
  __builtin_amdgcn_global_load_lds(
      (const __attribute__((address_space(1))) unsigned int*)g,
      (__attribute__((address_space(3))) unsigned int*)l,
      16, 0, 0);
}

// ---------------- fp32 -> bf16 weight conversion ----------------
__global__ __launch_bounds__(256) void f2b_kernel(
    const float* __restrict__ s, bfu* __restrict__ d, int n)
{
  int i = blockIdx.x*256 + threadIdx.x;
  if (i < n) d[i] = f2bu(s[i]);
}

// ======== cLN of x: partial stats (x is (B,C,T)) ========
__global__ __launch_bounds__(256) void clnA_f32(
    const float* __restrict__ X, float* __restrict__ part, int T)
{
  __shared__ float l1[4][64], l2[4][64];
  int tl = threadIdx.x & 63, w = threadIdx.x >> 6;
  int t0 = blockIdx.x*64, cb = blockIdx.y, b = blockIdx.z;
  const float* p = X + ((size_t)b*512 + cb*64)*T + t0 + tl;
  float s = 0.f, ss = 0.f;
#pragma unroll
  for (int c = 0; c < 16; c++){
    float v = p[(size_t)(c*4 + w)*T];
    s += v; ss += v*v;
  }
  l1[w][tl] = s; l2[w][tl] = ss;
  __syncthreads();
  if (w == 0){
    float S  = l1[0][tl]+l1[1][tl]+l1[2][tl]+l1[3][tl];
    float SS = l2[0][tl]+l2[1][tl]+l2[2][tl]+l2[3][tl];
    float* pp = part + (((size_t)b*8 + cb)*T + t0 + tl)*2;
    pp[0] = S; pp[1] = SS;
  }
}

// apply + transpose (stats folded in): x (B,C,T) -> out_cln,(x_btc) (B,T,C) bf16
__global__ __launch_bounds__(256) void clnC_trans(
    const float* __restrict__ X, const float* __restrict__ part,
    const float* __restrict__ w, const float* __restrict__ bb,
    bfu* __restrict__ OUT, bfu* __restrict__ XB, int T)
{
  __shared__ float Ls[64*65];
  __shared__ float smu[64], srs[64];
  int tl = threadIdx.x & 63, wv = threadIdx.x >> 6;
  int t0 = blockIdx.x*64, c0 = blockIdx.y*64, b = blockIdx.z;
#pragma unroll 4
  for (int r = 0; r < 16; r++){
    int c = c0 + wv*16 + r;
    Ls[(wv*16+r)*65 + tl] = X[((size_t)b*512 + c)*T + t0 + tl];
  }
  if (wv == 0){
    float S = 0.f, SS = 0.f;
#pragma unroll
    for (int cb = 0; cb < 8; cb++){
      const float* pp = part + (((size_t)b*8 + cb)*T + t0 + tl)*2;
      S += pp[0]; SS += pp[1];
    }
    float mu = S*(1.f/512.f);
    float var = SS*(1.f/512.f) - mu*mu;
    smu[tl] = mu; srs[tl] = rsqrtf(var + 1e-5f);
  }
  __syncthreads();
  float wc = w[c0 + tl], bc = bb[c0 + tl];
#pragma unroll 4
  for (int r = 0; r < 16; r++){
    int tr_ = wv*16 + r;
    float mu = smu[tr_], rs = srs[tr_];
    float xv = Ls[tl*65 + tr_];
    size_t o = ((size_t)b*T + t0 + tr_)*512 + c0 + tl;
    OUT[o] = f2bu((xv - mu)*rs*wc + bc);
    XB[o]  = f2bu(xv);
  }
}

// ---------------- phi partials + finalize ----------------
__global__ __launch_bounds__(256) void phiA(
    const bfu* __restrict__ oc, float* __restrict__ pp, int T)
{
  __shared__ float Ls[4][64];
  int tl = threadIdx.x & 63, wv = threadIdx.x >> 6;
  int t0 = blockIdx.x*64, c0 = blockIdx.y*64, b = blockIdx.z;
  float s = 0.f;
#pragma unroll 4
  for (int r = 0; r < 16; r++)
    s += bu2f(oc[((size_t)b*T + t0 + wv*16 + r)*512 + c0 + tl]);
  Ls[wv][tl] = s;
  __syncthreads();
  if (wv == 0){
    float tot = Ls[0][tl]+Ls[1][tl]+Ls[2][tl]+Ls[3][tl];
    pp[((size_t)b*512 + c0 + tl)*32 + blockIdx.x] = tot;
  }
}

__global__ __launch_bounds__(256) void phiB(
    const float* __restrict__ pp, const float* __restrict__ gw,
    const float* __restrict__ gb, float* __restrict__ phi, int T, int nch)
{
  int idx = blockIdx.x*256 + threadIdx.x;
  if (idx >= 1024) return;
  int c = idx & 511;
  float s = 0.f;
  for (int ch = 0; ch < nch; ch++) s += pp[(size_t)idx*32 + ch];
  phi[idx] = fmaxf((s/(float)T)*gw[c] + gb[c], 0.f);
}

// ---------------- fused prep + qkv depthwise convs, (B,T,C) ----------------
__global__ __launch_bounds__(256) void prepqkv(
    const bfu* __restrict__ oc, const float* __restrict__ phi,
    const float* __restrict__ psi_w, const float* __restrict__ psi_b,
    const float* __restrict__ cw_w, const float* __restrict__ cw_b,
    const float* __restrict__ ckw_w, const float* __restrict__ ckw_b, int ckw_k,
    const float* __restrict__ fc_w, const float* __restrict__ fc_b,
    const float* __restrict__ dw,
    bfu* __restrict__ qpre, bfu* __restrict__ kpre, bfu* __restrict__ vpre, int T)
{
  int idx = blockIdx.x*256 + threadIdx.x;
  if (idx >= 2*T*512) return;
  int c = idx & 511, tc = idx >> 9, t = tc % T, b = tc / T;
  const bfu* base = oc + ((size_t)b*T)*512 + c;
  float w7[7];
#pragma unroll
  for (int o = 0; o < 7; o++){
    int tt = t + o - 3;
    w7[o] = (tt >= 0 && tt < T) ? bu2f(base[(size_t)tt*512]) : 0.f;
  }
  float phic = phi[b*512 + c];
  float psb = psi_b[c], cwb = cw_b[c], ckb = ckw_b[c];
  float fw = fc_w[c], fb = fc_b[c];
  float xat[3], yv[3];
#pragma unroll
  for (int k = 0; k < 3; k++){
    int tt = t + k - 1;
    if (tt < 0 || tt >= T){ xat[k] = 0.f; yv[k] = 0.f; continue; }
    int ci = 2 + k;
    float psi = psb, cw = cwb;
#pragma unroll
    for (int j = 0; j < 3; j++){
      psi += w7[ci-1+j]*psi_w[c*3+j];
      cw  += w7[ci-1+j]*cw_w[c*3+j];
    }
    float ck = ckb;
    if (ckw_k == 1)      ck += w7[ci]*ckw_w[c];
    else if (ckw_k == 3){
#pragma unroll
      for (int j = 0; j < 3; j++) ck += w7[ci-1+j]*ckw_w[c*3+j];
    } else {
#pragma unroll
      for (int j = 0; j < 5; j++) ck += w7[ci-2+j]*ckw_w[c*5+j];
    }
    xat[k] = (cw + ck)*psi;
    yv[k]  = (w7[ci]*fw + fb)*phic;
  }
  float q = 0.f, kk = 0.f, v = 0.f;
#pragma unroll
  for (int j = 0; j < 3; j++){
    q  += xat[j]*dw[0*1536 + c*3 + j];
    kk += yv[j]*dw[1*1536 + c*3 + j];
    v  += yv[j]*dw[2*1536 + c*3 + j];
  }
  qpre[idx] = f2bu(q); kpre[idx] = f2bu(kk); vpre[idx] = f2bu(v);
}

// ---------------- cLN of q/k/v (B,T,C): one wave per row ----------------
__global__ __launch_bounds__(256) void cln3_kernel(
    bfu* __restrict__ Q, size_t slotStride, const float* __restrict__ nw,
    const float* __restrict__ nb, int T)
{
  int lane = threadIdx.x & 63, w = threadIdx.x >> 6;
  int row = blockIdx.x*4 + w;
  int j = row / (2*T), bt = row % (2*T);
  bfu* p = Q + (size_t)j*slotStride + (size_t)bt*512 + lane*8;
  short8 sv = *(short8*)p;
  float f[8]; float s = 0.f, ss = 0.f;
#pragma unroll
  for (int e = 0; e < 8; e++){
    f[e] = bu2f((bfu)sv[e]); s += f[e]; ss += f[e]*f[e];
  }
#pragma unroll
  for (int off = 1; off < 64; off <<= 1){
    s += __shfl_xor(s, off, 64); ss += __shfl_xor(ss, off, 64);
  }
  float mu = s*(1.f/512.f);
  float var = ss*(1.f/512.f) - mu*mu;
  float rs = rsqrtf(var + 1e-5f);
  const float* nwp = nw + j*512 + lane*8;
  const float* nbp = nb + j*512 + lane*8;
  short8 ov;
#pragma unroll
  for (int e = 0; e < 8; e++)
    ov[e] = (short)f2bu((f[e]-mu)*rs*nwp[e] + nbp[e]);
  *(short8*)p = ov;
}

// ---------------- residual pre-sum: res = out_cln + x_btc (in-place on x_btc) ----------------
__global__ __launch_bounds__(256) void resadd_kernel(
    const bfu* __restrict__ a, bfu* __restrict__ b_, int n)
{
  int i = blockIdx.x*256 + threadIdx.x;
  if (i < n) b_[i] = f2bu(bu2f(a[i]) + bu2f(b_[i]));
}

// ---------------- GEMM core 128x128x32 (m97 staging). TR swaps MFMA operands ----------------
template<bool TR>
__device__ __forceinline__ void mm_core(
    const bfu* __restrict__ Xb, const bfu* __restrict__ Wb, int K,
    short* As, short* Bs, int tid, floatx4 acc[4][4])
{
  const int lane = tid & 63, w = tid >> 6;
  const int quad = lane >> 4, l16 = lane & 15;
  const int wt = (w >> 1)*64, wn = (w & 1)*64;
  const int srow = lane >> 2, skoff = (lane & 3)*8;
  const int r0 = w*32;
  bfu* ldsA0 = (bfu*)&As[(r0)*32];
  bfu* ldsA1 = (bfu*)&As[(r0+16)*32];
  bfu* ldsB0 = (bfu*)&Bs[(r0)*32];
  bfu* ldsB1 = (bfu*)&Bs[(r0+16)*32];
  const bfu* gA0 = Xb + (size_t)(r0 + srow)*K + skoff;
  const bfu* gA1 = Xb + (size_t)(r0 + 16 + srow)*K + skoff;
  const bfu* gB0 = Wb + (size_t)(r0 + srow)*K + skoff;
  const bfu* gB1 = Wb + (size_t)(r0 + 16 + srow)*K + skoff;

  for (int k0 = 0; k0 < K; k0 += 32){
    __syncthreads();
    gld16(gA0 + k0, ldsA0);
    gld16(gA1 + k0, ldsA1);
    gld16(gB0 + k0, ldsB0);
    gld16(gB1 + k0, ldsB1);
    __syncthreads();
    short8 af[4], bf[4];
#pragma unroll
    for (int i = 0; i < 4; i++) af[i] = *(short8*)&As[(wt + i*16 + l16)*32 + quad*8];
#pragma unroll
    for (int i = 0; i < 4; i++) bf[i] = *(short8*)&Bs[(wn + i*16 + l16)*32 + quad*8];
#pragma unroll
    for (int i = 0; i < 4; i++)
#pragma unroll
      for (int j = 0; j < 4; j++){
        if (TR) acc[i][j] = __builtin_amdgcn_mfma_f32_16x16x32_bf16(bf[i], af[j], acc[i][j], 0,0,0);
        else    acc[i][j] = __builtin_amdgcn_mfma_f32_16x16x32_bf16(af[i], bf[j], acc[i][j], 0,0,0);
      }
  }
}

// plain GEMM: OUT (B,T,M) = X (B,T,K) · W(M,K)^T + bias (+res) (gelu)
__global__ __launch_bounds__(256) void gemm128(
    const bfu* __restrict__ X, const bfu* __restrict__ W,
    const float* __restrict__ bias, bfu* __restrict__ OUT,
    const bfu* __restrict__ res1,
    int T, int M, int K, int gelu)
{
  __shared__ __align__(16) short As[128*32];
  __shared__ __align__(16) short Bs[128*32];
  const int b = blockIdx.z;
  const int t0 = blockIdx.x*128, m0 = blockIdx.y*128;
  const int tid = threadIdx.x, lane = tid & 63;
  const int quad = lane >> 4, l16 = lane & 15;
  const int w = tid >> 6, wt = (w >> 1)*64, wn = (w & 1)*64;

  floatx4 acc[4][4];
#pragma unroll
  for (int i = 0; i < 4; i++)
#pragma unroll
    for (int j = 0; j < 4; j++) acc[i][j] = (floatx4){0.f,0.f,0.f,0.f};

  mm_core<false>(X + ((size_t)b*T + t0)*K, W + (size_t)m0*K, K, As, Bs, tid, acc);

  size_t ob = (size_t)b*T;
#pragma unroll
  for (int ti = 0; ti < 4; ti++){
    int t = t0 + wt + ti*16 + quad*4;
#pragma unroll
    for (int mi = 0; mi < 4; mi++){
      int m = m0 + wn + mi*16 + l16;
      float bi = bias[m];
#pragma unroll
      for (int i = 0; i < 4; i++){
        size_t o = (ob + t + i)*(size_t)M + m;
        float v = acc[ti][mi][i] + bi;
        if (res1) v += bu2f(res1[o]);
        if (gelu) v = 0.5f*v*(1.f + erff(v*0.70710678f));
        OUT[o] = f2bu(v);
      }
    }
  }
}

// merged q/k/v GEMM; which==2 (V) stores transposed (B,M,T) via operand swap
struct QKV3 {
  const bfu* X[3]; const bfu* W[3]; const float* bias[3]; bfu* O[3];
};
__global__ __launch_bounds__(256) void qkv_gemm(QKV3 a, int T)
{
  __shared__ __align__(16) short As[128*32];
  __shared__ __align__(16) short Bs[128*32];
  const int z = blockIdx.z, b = z & 1, which = z >> 1;
  const int t0 = blockIdx.x*128, m0 = blockIdx.y*128;
  const int tid = threadIdx.x, lane = tid & 63;
  const int quad = lane >> 4, l16 = lane & 15;
  const int w = tid >> 6, wt = (w >> 1)*64, wn = (w & 1)*64;
  const bfu* Xb = a.X[which] + ((size_t)b*T + t0)*512;
  const bfu* Wb = a.W[which] + (size_t)m0*512;
  const float* bias = a.bias[which];
  bfu* O = a.O[which];

  floatx4 acc[4][4];
#pragma unroll
  for (int i = 0; i < 4; i++)
#pragma unroll
    for (int j = 0; j < 4; j++) acc[i][j] = (floatx4){0.f,0.f,0.f,0.f};

  if (which == 2){
    mm_core<true>(Xb, Wb, 512, As, Bs, tid, acc);
#pragma unroll
    for (int mi = 0; mi < 4; mi++){
      int m = m0 + wn + mi*16 + quad*4;
#pragma unroll
      for (int ti = 0; ti < 4; ti++){
        int t = t0 + wt + ti*16 + l16;
#pragma unroll
        for (int i = 0; i < 4; i++)
          O[((size_t)b*512 + m + i)*T + t] = f2bu(acc[mi][ti][i] + bias[m + i]);
      }
    }
  } else {
    mm_core<false>(Xb, Wb, 512, As, Bs, tid, acc);
    size_t ob = (size_t)b*T;
#pragma unroll
    for (int ti = 0; ti < 4; ti++){
      int t = t0 + wt + ti*16 + quad*4;
#pragma unroll
      for (int mi = 0; mi < 4; mi++){
        int m = m0 + wn + mi*16 + l16;
        float bi = bias[m];
#pragma unroll
        for (int i = 0; i < 4; i++)
          O[(ob + t + i)*512 + m] = f2bu(acc[ti][mi][i] + bi);
      }
    }
  }
}

// ---------------- flash attention: S^T formulation, zero LDS, max-free softmax ----------------
// S^T = mfma(A=K, B=Q): C-layout row=s(quad*4+i), col=t(l16) — identity-feeds the
// B operand (n=l16, k=quad*4+j) of v_mfma_f32_16x16x16_bf16 for PV: O^T = V·P^T.
// grid (16 bh -> XCD pin, T/64 qtile, nsp). po in (b,c,t) across 4 planes; lbuf row sums.
struct POP { bfu* p[4]; };
__global__ __launch_bounds__(256, 4) void attn_kernel(
    const bfu* __restrict__ Q, const bfu* __restrict__ K,
    const bfu* __restrict__ V, POP po, float* __restrict__ lbuf,
    int T, int nsp)
{
  int bh = blockIdx.x, b = bh >> 3, h = bh & 7;
  int t0 = blockIdx.y*64;
  int sp = blockIdx.z, chunk = T/nsp, s_begin = sp*chunk;
  int tid = threadIdx.x, lane = tid & 63, w = tid >> 6;
  int quad = lane >> 4, l16 = lane & 15, qw = w*16;
  const bfu* Qb = Q + ((size_t)b*T)*512 + h*64;
  const bfu* Kb = K + ((size_t)b*T)*512 + h*64;
  const bfu* Vb = V + ((size_t)b*512 + h*64)*T;

  // Q fragment (B operand): rows t0+qw+l16, k=d
  const bfu* qrow = Qb + (size_t)(t0 + qw + l16)*512;
  short8 q0 = *(const short8*)&qrow[quad*8];
  short8 q1 = *(const short8*)&qrow[32 + quad*8];

  floatx4 o[4];   // O^T: row d=dn*16+quad*4+i, col t=qw+l16
#pragma unroll
  for (int i = 0; i < 4; i++) o[i] = (floatx4){0.f,0.f,0.f,0.f};
  float lsum = 0.f;
  const float C8 = 0.18033688f;   // 0.125 * log2(e); scores bounded, max-free safe (R7-verified)

  for (int s0 = s_begin; s0 < s_begin + chunk; s0 += 64){
    floatx4 st[4];
#pragma unroll
    for (int sn = 0; sn < 4; sn++){
      const bfu* krow = Kb + (size_t)(s0 + sn*16 + l16)*512;
      short8 k0 = *(const short8*)&krow[quad*8];
      short8 k1 = *(const short8*)&krow[32 + quad*8];
      floatx4 acc = (floatx4){0.f,0.f,0.f,0.f};
      acc = __builtin_amdgcn_mfma_f32_16x16x32_bf16(k0, q0, acc, 0,0,0);
      acc = __builtin_amdgcn_mfma_f32_16x16x32_bf16(k1, q1, acc, 0,0,0);
      st[sn] = acc;
    }
#pragma unroll
    for (int sn = 0; sn < 4; sn++){
      sh4 pf;
#pragma unroll
      for (int i = 0; i < 4; i++){
        float p = exp2f(st[sn][i]*C8);
        lsum += p;
        pf[i] = (short)f2bu(p);
      }
#pragma unroll
      for (int dn = 0; dn < 4; dn++){
        const sh4* vp = (const sh4*)(Vb + (size_t)(dn*16 + l16)*T + s0 + sn*16 + quad*4);
        o[dn] = __builtin_amdgcn_mfma_f32_16x16x16bf16_1k(*vp, pf, o[dn], 0,0,0);
      }
    }
  }

  // row sum shared across quads (col t = l16): butterfly over lane^16, lane^32
  lsum += __shfl_xor(lsum, 16, 64);
  lsum += __shfl_xor(lsum, 32, 64);
  float linv = 1.f / lsum;

  size_t lin = (size_t)sp * 1024 * T;            // sp region in elements (B*512*T)
  bfu* Pp = po.p[lin >> 21] + (lin & 2097151) + ((size_t)b*512 + h*64)*T;
#pragma unroll
  for (int dn = 0; dn < 4; dn++)
#pragma unroll
    for (int i = 0; i < 4; i++)
      Pp[(size_t)(dn*16 + quad*4 + i)*T + t0 + qw + l16] = f2bu(o[dn][i] * linv);
  if (quad == 0)
    lbuf[(size_t)(sp*16 + bh)*T + t0 + qw + l16] = lsum;
}

// ---------------- combine split partials (b,c,t) -> attout (B,T,C) via LDS transpose ----------------
__global__ __launch_bounds__(256) void attn_combine_kernel(
    POP po, const float* __restrict__ lbuf, bfu* __restrict__ attout, int T, int nsp)
{
  __shared__ short Ls[64*65];
  int tl = threadIdx.x & 63, wv = threadIdx.x >> 6;
  int t0 = blockIdx.x*64, h = blockIdx.y, b = blockIdx.z;
  int t = t0 + tl;
  float l[8]; float wsum = 0.f;
  for (int sp = 0; sp < nsp; sp++){
    l[sp] = lbuf[(size_t)(sp*16 + b*8 + h)*T + t];
    wsum += l[sp];
  }
  float winv = 1.f / wsum;
#pragma unroll 4
  for (int r = 0; r < 16; r++){
    int cl = wv*16 + r;
    float acc = 0.f;
    for (int sp = 0; sp < nsp; sp++){
      size_t lin = (size_t)sp * 1024 * T;
      const bfu* Pb = po.p[lin >> 21] + (lin & 2097151);
      acc += l[sp] * bu2f(Pb[((size_t)b*512 + h*64 + cl)*T + t]);
    }
    Ls[cl*65 + tl] = (short)f2bu(acc * winv);
  }
  __syncthreads();
#pragma unroll 4
  for (int r = 0; r < 16; r++){
    int tt = t0 + wv*16 + r;
    attout[((size_t)b*T + tt)*512 + h*64 + tl] = (bfu)Ls[tl*65 + wv*16 + r];
  }
}

// ---------------- GroupNorm partials / fused finalize+apply, (B,T,C) ----------------
__global__ __launch_bounds__(256) void gnA(
    const bfu* __restrict__ X, float* __restrict__ pgn, int T)
{
  __shared__ float L1[4][64], L2[4][64];
  int tl = threadIdx.x & 63, wv = threadIdx.x >> 6;
  int t0 = blockIdx.x*64, cb = blockIdx.y, b = blockIdx.z;
  int c0 = cb*64;
  float s = 0.f, ss = 0.f;
#pragma unroll 4
  for (int r = 0; r < 16; r++){
    float v = bu2f(X[((size_t)b*T + t0 + wv*16 + r)*512 + c0 + tl]);
    s += v; ss += v*v;
  }
  L1[wv][tl] = s; L2[wv][tl] = ss;
  __syncthreads();
  if (wv == 0){
    float cs  = L1[0][tl]+L1[1][tl]+L1[2][tl]+L1[3][tl];
    float css = L2[0][tl]+L2[1][tl]+L2[2][tl]+L2[3][tl];
#pragma unroll
    for (int off = 1; off < 32; off <<= 1){
      cs  += __shfl_xor(cs,  off, 32);
      css += __shfl_xor(css, off, 32);
    }
    if (tl == 0 || tl == 32){
      int g = cb*2 + (tl >> 5);
      float* pp = pgn + (((size_t)b*16 + g)*32 + blockIdx.x)*2;
      pp[0] = cs; pp[1] = css;
    }
  }
}

__global__ __launch_bounds__(256) void gnapply_kernel(
    const bfu* __restrict__ X, const float* __restrict__ pgn,
    const float* __restrict__ w, const float* __restrict__ bb,
    bfu* __restrict__ OUT, int T, int nch)
{
  __shared__ float smu[8], srs[8];
  int idx = blockIdx.x*256 + threadIdx.x;
  int c = idx & 511, b = (idx >> 9) / T;
  int tid = threadIdx.x;
  if (tid < 8){
    int c0 = (blockIdx.x*256) & 511;
    int g = (c0 >> 5) + tid;
    float S = 0.f, SS = 0.f;
    for (int ch = 0; ch < nch; ch++){
      const float* pp = pgn + (((size_t)b*16 + g)*32 + ch)*2;
      S += pp[0]; SS += pp[1];
    }
    float n = 32.f*(float)T;
    float mu = S/n, var = SS/n - mu*mu;
    smu[tid] = mu; srs[tid] = rsqrtf(var + 1e-5f);
  }
  __syncthreads();
  if (idx >= 2*T*512) return;
  int gl = (c >> 5) & 7;
  float mu = smu[gl], rs = srs[gl];
  OUT[idx] = f2bu((bu2f(X[idx]) - mu)*rs*w[c] + bb[c]);
}

// ---------------- final: (B,T,C) bf16 -> d_out (B,C,T) fp32 ----------------
__global__ __launch_bounds__(256) void trans_out(
    const bfu* __restrict__ IN, float* __restrict__ OUT, int T)
{
  __shared__ float Ls[64*65];
  int tl = threadIdx.x & 63, wv = threadIdx.x >> 6;
  int t0 = blockIdx.x*64, c0 = blockIdx.y*64, b = blockIdx.z;
#pragma unroll 4
  for (int r = 0; r < 16; r++){
    int t = t0 + wv*16 + r;
    Ls[tl*65 + wv*16 + r] = bu2f(IN[((size_t)b*T + t)*512 + c0 + tl]);
  }
  __syncthreads();
#pragma unroll 4
  for (int r = 0; r < 16; r++){
    int c = c0 + wv*16 + r;
    OUT[((size_t)b*512 + c)*T + t0 + tl] = Ls[(wv*16+r)*65 + tl];
  }
}

// ---------------- launch ----------------
extern "C" void kernel_launch(void* const* d_in, const int* in_sizes, int n_in,
                              void* d_out, int out_size, void* d_ws, size_t ws_size,
                              hipStream_t stream)
{
  (void)in_sizes; (void)n_in; (void)out_size; (void)ws_size;
  const int B = 2;
  const float* xs_in[3] = {(const float*)d_in[0], (const float*)d_in[1], (const float*)d_in[2]};
  const int Ts[3] = {512, 1024, 2048};
  const float* ln_w   = (const float*)d_in[6];
  const float* ln_b   = (const float*)d_in[7];
  const float* gn_w   = (const float*)d_in[8];
  const float* gn_b   = (const float*)d_in[9];
  const float* psi_w  = (const float*)d_in[10];
  const float* psi_b  = (const float*)d_in[11];
  const float* fc_w   = (const float*)d_in[12];
  const float* fc_b   = (const float*)d_in[13];
  const float* convw_w = (const float*)d_in[14];
  const float* convw_b = (const float*)d_in[15];
  const float* ckw_ws[3] = {(const float*)d_in[16], (const float*)d_in[18], (const float*)d_in[20]};
  const float* ckw_bs[3] = {(const float*)d_in[17], (const float*)d_in[19], (const float*)d_in[21]};
  const int   ckw_ks[3] = {1, 3, 5};
  const float* gfc_w  = (const float*)d_in[22];
  const float* gfc_b  = (const float*)d_in[23];
  const float* ca_dw  = (const float*)d_in[24];
  const float* ca_nw  = (const float*)d_in[25];
  const float* ca_nb  = (const float*)d_in[26];
  const float* qkv_w  = (const float*)d_in[27];
  const float* qkv_b  = (const float*)d_in[28];
  const float* proj_w = (const float*)d_in[29];
  const float* proj_b = (const float*)d_in[30];
  const float* mlp1_w = (const float*)d_in[31];
  const float* mlp1_b = (const float*)d_in[32];
  const float* mlp2_w = (const float*)d_in[33];
  const float* mlp2_b = (const float*)d_in[34];

  char* ws = (char*)d_ws;
  const size_t P = (size_t)2*2048*512*2;   // 4 MB plane
  const size_t PS = P/2;
  // slot map (lifetimes audited):
  // s0: out_cln -> [prepqkv,phiA,resadd] ; then po plane0 ; then hidden[0]
  // s1: x_btc -> resadd(in-place sum)    ; res for proj   ; then hidden[1]
  // s2: qpre -> qkv ; po plane1 ; hidden[2]
  // s3: kpre -> qkv ; po plane2 ; hidden[3]
  // s4: vpre -> qkv ; po plane3 ; mlp2out
  // s5: vbuf -> attn ; gnout
  // s6: qbuf -> attn ; attout
  // s7: kbuf -> attn ; resb
  bfu* out_cln = (bfu*)(ws + 0*P);
  bfu* x_btc   = (bfu*)(ws + 1*P);
  bfu* qpre    = (bfu*)(ws + 2*P);
  bfu* kpre    = (bfu*)(ws + 3*P);
  bfu* vpre    = (bfu*)(ws + 4*P);
  bfu* vbuf    = (bfu*)(ws + 5*P);
  bfu* qbuf    = (bfu*)(ws + 6*P);
  bfu* kbuf    = (bfu*)(ws + 7*P);
  bfu* attout  = qbuf;
  bfu* resb    = kbuf;
  bfu* gnout   = vbuf;
  bfu* hidden  = out_cln;
  bfu* mlp2out = vpre;
  bfu* wqkvB  = (bfu*)(ws + 8*P);
  bfu* wprojB = wqkvB + 3*512*512;
  bfu* wm1B   = wprojB + 512*512;
  bfu* wm2B   = wm1B + 2048*512;
  float* part  = (float*)((char*)(wm2B + 512*2048));  // 65536 f
  float* pp    = part + 65536;                        // 32768 f
  float* phi   = pp + 32768;                          // 1024 f
  float* lbuf  = phi + 1024;                          // 131072 f
  float* pgn   = lbuf + 131072;                       // 2048 f

  f2b_kernel<<<(3*512*512+255)/256, 256, 0, stream>>>(qkv_w,  wqkvB, 3*512*512);
  f2b_kernel<<<(512*512+255)/256,   256, 0, stream>>>(proj_w, wprojB, 512*512);
  f2b_kernel<<<(2048*512+255)/256,  256, 0, stream>>>(mlp1_w, wm1B, 2048*512);
  f2b_kernel<<<(2048*512+255)/256,  256, 0, stream>>>(mlp2_w, wm2B, 512*2048);

  size_t out_off = 0;
  for (int bi = 0; bi < 3; bi++){
    int T = Ts[bi];
    int nsp = (T == 2048) ? 4 : 8;      // 2048/2048/1024 attn blocks
    int nch = T / 64;
    const float* x = xs_in[bi];
    float* outp = (float*)d_out + out_off;
    int nelem = B*512*T;
    dim3 eb((nelem + 255)/256);

    clnA_f32<<<dim3(T/64, 8, B), 256, 0, stream>>>(x, part, T);
    clnC_trans<<<dim3(T/64, 8, B), 256, 0, stream>>>(x, part, ln_w, ln_b, out_cln, x_btc, T);

    phiA<<<dim3(T/64, 8, B), 256, 0, stream>>>(out_cln, pp, T);
    phiB<<<4, 256, 0, stream>>>(pp, gfc_w, gfc_b, phi, T, nch);

    prepqkv<<<eb, 256, 0, stream>>>(out_cln, phi, psi_w, psi_b,
        convw_w + bi*512*3, convw_b + bi*512, ckw_ws[bi], ckw_bs[bi], ckw_ks[bi],
        fc_w, fc_b, ca_dw, qpre, kpre, vpre, T);
    cln3_kernel<<<(3*B*T)/4, 256, 0, stream>>>(qpre, PS, ca_nw, ca_nb, T);

    QKV3 qa;
    qa.X[0] = qpre;  qa.X[1] = kpre;  qa.X[2] = vpre;
    qa.W[0] = wqkvB; qa.W[1] = wqkvB + 262144; qa.W[2] = wqkvB + 524288;
    qa.bias[0] = qkv_b; qa.bias[1] = qkv_b + 512; qa.bias[2] = qkv_b + 1024;
    qa.O[0] = qbuf; qa.O[1] = kbuf; qa.O[2] = vbuf;
    qkv_gemm<<<dim3(T/128, 4, 6), 256, 0, stream>>>(qa, T);

    resadd_kernel<<<eb, 256, 0, stream>>>(out_cln, x_btc, nelem);

    POP pos; pos.p[0] = out_cln; pos.p[1] = qpre; pos.p[2] = kpre; pos.p[3] = vpre;
    attn_kernel<<<dim3(16, T/64, nsp), 256, 0, stream>>>(qbuf, kbuf, vbuf, pos, lbuf, T, nsp);
    attn_combine_kernel<<<dim3(T/64, 8, B), 256, 0, stream>>>(pos, lbuf, attout, T, nsp);

    gemm128<<<dim3(T/128, 4, B), 256, 0, stream>>>(attout, wprojB, proj_b, resb, x_btc, T, 512, 512, 0);

    gnA<<<dim3(T/64, 8, B), 256, 0, stream>>>(resb, pgn, T);
    gnapply_kernel<<<eb, 256, 0, stream>>>(resb, pgn, gn_w, gn_b, gnout, T, nch);

    gemm128<<<dim3(T/128, 16, B), 256, 0, stream>>>(gnout, wm1B, mlp1_b, hidden, nullptr, T, 2048, 512, 1);
    gemm128<<<dim3(T/128, 4, B), 256, 0, stream>>>(hidden, wm2B, mlp2_b, mlp2out, resb, T, 512, 2048, 0);

    trans_out<<<dim3(T/64, 8, B), 256, 0, stream>>>(mlp2out, outp, T);

    out_off += (size_t)nelem;
  }
}

// Round 9
// 771.551 us; speedup vs baseline: 1.3210x; 1.3210x over previous
//
#include <hip/hip_runtime.h>
#include <math.h>

typedef unsigned short bfu;   // raw bf16 bits
typedef __attribute__((ext_vector_type(8))) short short8;
typedef __attribute__((ext_vector_type(4))) float floatx4;

__device__ __forceinline__ float bu2f(bfu u){
  return __builtin_bit_cast(float, (unsigned)u << 16);
}
__device__ __forceinline__ bfu f2bu(float f){
  unsigned x = __builtin_bit_cast(unsigned, f);
  unsigned r = (x + 0x7FFFu + ((x >> 16) & 1u)) >> 16;   // RNE
  return (bfu)r;
}
__device__ __forceinline__ void gld16(const bfu* g, bfu* l){
  __builtin_amdgcn_global_load_lds(
      (const __attribute__((address_space(1))) unsigned int*)g,
      (__attribute__((address_space(3))) unsigned int*)l,
      16, 0, 0);
}

// ---------------- fp32 -> bf16 weight conversion, all 4 weights in one dispatch ----------------
struct F2B { const float* s[4]; bfu* d[4]; int n[4]; };
__global__ __launch_bounds__(256) void f2b_all(F2B a)
{
  int j = blockIdx.y;
  int i = blockIdx.x*256 + threadIdx.x;
  if (i < a.n[j]) a.d[j][i] = f2bu(a.s[j][i]);
}

// ======== cLN of x: partial stats (x is (B,C,T)) ========
__global__ __launch_bounds__(256) void clnA_f32(
    const float* __restrict__ X, float* __restrict__ part, int T)
{
  __shared__ float l1[4][64], l2[4][64];
  int tl = threadIdx.x & 63, w = threadIdx.x >> 6;
  int t0 = blockIdx.x*64, cb = blockIdx.y, b = blockIdx.z;
  const float* p = X + ((size_t)b*512 + cb*64)*T + t0 + tl;
  float s = 0.f, ss = 0.f;
#pragma unroll
  for (int c = 0; c < 16; c++){
    float v = p[(size_t)(c*4 + w)*T];
    s += v; ss += v*v;
  }
  l1[w][tl] = s; l2[w][tl] = ss;
  __syncthreads();
  if (w == 0){
    float S  = l1[0][tl]+l1[1][tl]+l1[2][tl]+l1[3][tl];
    float SS = l2[0][tl]+l2[1][tl]+l2[2][tl]+l2[3][tl];
    float* pp = part + (((size_t)b*8 + cb)*T + t0 + tl)*2;
    pp[0] = S; pp[1] = SS;
  }
}

// apply + transpose + phi column-partials: x (B,C,T) -> out_cln,x_btc (B,T,C) bf16; pp partial sums
__global__ __launch_bounds__(256) void clnC_trans(
    const float* __restrict__ X, const float* __restrict__ part,
    const float* __restrict__ w, const float* __restrict__ bb,
    bfu* __restrict__ OUT, bfu* __restrict__ XB, float* __restrict__ pp, int T)
{
  __shared__ float Ls[64*65];
  __shared__ float smu[64], srs[64];
  __shared__ float ph[4][64];
  int tl = threadIdx.x & 63, wv = threadIdx.x >> 6;
  int t0 = blockIdx.x*64, c0 = blockIdx.y*64, b = blockIdx.z;
#pragma unroll 4
  for (int r = 0; r < 16; r++){
    int c = c0 + wv*16 + r;
    Ls[(wv*16+r)*65 + tl] = X[((size_t)b*512 + c)*T + t0 + tl];
  }
  if (wv == 0){
    float S = 0.f, SS = 0.f;
#pragma unroll
    for (int cb = 0; cb < 8; cb++){
      const float* pq = part + (((size_t)b*8 + cb)*T + t0 + tl)*2;
      S += pq[0]; SS += pq[1];
    }
    float mu = S*(1.f/512.f);
    float var = SS*(1.f/512.f) - mu*mu;
    smu[tl] = mu; srs[tl] = rsqrtf(var + 1e-5f);
  }
  __syncthreads();
  float wc = w[c0 + tl], bc = bb[c0 + tl];
  float psum = 0.f;
#pragma unroll 4
  for (int r = 0; r < 16; r++){
    int tr_ = wv*16 + r;
    float mu = smu[tr_], rs = srs[tr_];
    float xv = Ls[tl*65 + tr_];
    float ov = (xv - mu)*rs*wc + bc;
    size_t o = ((size_t)b*T + t0 + tr_)*512 + c0 + tl;
    OUT[o] = f2bu(ov);
    XB[o]  = f2bu(xv);
    psum += ov;
  }
  __syncthreads();
  ph[wv][tl] = psum;
  __syncthreads();
  if (wv == 0)
    pp[((size_t)b*512 + c0 + tl)*32 + blockIdx.x] = ph[0][tl]+ph[1][tl]+ph[2][tl]+ph[3][tl];
}

__global__ __launch_bounds__(256) void phiB(
    const float* __restrict__ pp, const float* __restrict__ gw,
    const float* __restrict__ gb, float* __restrict__ phi, int T, int nch)
{
  int idx = blockIdx.x*256 + threadIdx.x;
  if (idx >= 1024) return;
  int c = idx & 511;
  float s = 0.f;
  for (int ch = 0; ch < nch; ch++) s += pp[(size_t)idx*32 + ch];
  phi[idx] = fmaxf((s/(float)T)*gw[c] + gb[c], 0.f);
}

// ---------------- fused prep + qkv depthwise convs + q/k/v cLN; block=512 = one (b,t) row ----------------
__global__ __launch_bounds__(512) void prepqkv(
    const bfu* __restrict__ oc, const float* __restrict__ phi,
    const float* __restrict__ psi_w, const float* __restrict__ psi_b,
    const float* __restrict__ cw_w, const float* __restrict__ cw_b,
    const float* __restrict__ ckw_w, const float* __restrict__ ckw_b, int ckw_k,
    const float* __restrict__ fc_w, const float* __restrict__ fc_b,
    const float* __restrict__ dw, const float* __restrict__ nw, const float* __restrict__ nb,
    bfu* __restrict__ qpre, bfu* __restrict__ kpre, bfu* __restrict__ vpre, int T)
{
  __shared__ float red[8][6];
  __shared__ float stat[6];
  int c = threadIdx.x;
  int bt = blockIdx.x, t = bt % T, b = bt / T;
  const bfu* base = oc + ((size_t)b*T)*512 + c;
  float w7[7];
#pragma unroll
  for (int o = 0; o < 7; o++){
    int tt = t + o - 3;
    w7[o] = (tt >= 0 && tt < T) ? bu2f(base[(size_t)tt*512]) : 0.f;
  }
  float phic = phi[b*512 + c];
  float psb = psi_b[c], cwb = cw_b[c], ckb = ckw_b[c];
  float fw = fc_w[c], fb = fc_b[c];
  float xat[3], yv[3];
#pragma unroll
  for (int k = 0; k < 3; k++){
    int tt = t + k - 1;
    if (tt < 0 || tt >= T){ xat[k] = 0.f; yv[k] = 0.f; continue; }
    int ci = 2 + k;
    float psi = psb, cw = cwb;
#pragma unroll
    for (int j = 0; j < 3; j++){
      psi += w7[ci-1+j]*psi_w[c*3+j];
      cw  += w7[ci-1+j]*cw_w[c*3+j];
    }
    float ck = ckb;
    if (ckw_k == 1)      ck += w7[ci]*ckw_w[c];
    else if (ckw_k == 3){
#pragma unroll
      for (int j = 0; j < 3; j++) ck += w7[ci-1+j]*ckw_w[c*3+j];
    } else {
#pragma unroll
      for (int j = 0; j < 5; j++) ck += w7[ci-2+j]*ckw_w[c*5+j];
    }
    xat[k] = (cw + ck)*psi;
    yv[k]  = (w7[ci]*fw + fb)*phic;
  }
  float q = 0.f, kk = 0.f, v = 0.f;
#pragma unroll
  for (int j = 0; j < 3; j++){
    q  += xat[j]*dw[0*1536 + c*3 + j];
    kk += yv[j]*dw[1*1536 + c*3 + j];
    v  += yv[j]*dw[2*1536 + c*3 + j];
  }
  // fused cLN over the row (biased var over C=512)
  float v6[6] = {q, q*q, kk, kk*kk, v, v*v};
#pragma unroll
  for (int off = 1; off < 64; off <<= 1)
#pragma unroll
    for (int e = 0; e < 6; e++) v6[e] += __shfl_xor(v6[e], off, 64);
  int wv = threadIdx.x >> 6;
  if ((threadIdx.x & 63) == 0){
#pragma unroll
    for (int e = 0; e < 6; e++) red[wv][e] = v6[e];
  }
  __syncthreads();
  if (threadIdx.x < 3){
    int j = threadIdx.x;
    float S = 0.f, SS = 0.f;
#pragma unroll
    for (int k = 0; k < 8; k++){ S += red[k][j*2]; SS += red[k][j*2+1]; }
    float mu = S*(1.f/512.f);
    float var = SS*(1.f/512.f) - mu*mu;
    stat[j*2] = mu; stat[j*2+1] = rsqrtf(var + 1e-5f);
  }
  __syncthreads();
  size_t o = (size_t)bt*512 + c;
  qpre[o] = f2bu((q  - stat[0])*stat[1]*nw[c]        + nb[c]);
  kpre[o] = f2bu((kk - stat[2])*stat[3]*nw[512 + c]  + nb[512 + c]);
  vpre[o] = f2bu((v  - stat[4])*stat[5]*nw[1024 + c] + nb[1024 + c]);
}

// ---------------- residual pre-sum: x_btc += out_cln (frees out_cln plane for po) ----------------
__global__ __launch_bounds__(256) void resadd_kernel(
    const bfu* __restrict__ a, bfu* __restrict__ b_, int n)
{
  int i = blockIdx.x*256 + threadIdx.x;
  if (i < n) b_[i] = f2bu(bu2f(a[i]) + bu2f(b_[i]));
}

// ---------------- GEMM core 128x128x32 (m97 staging). TR swaps MFMA operands ----------------
template<bool TR>
__device__ __forceinline__ void mm_core(
    const bfu* __restrict__ Xb, const bfu* __restrict__ Wb, int K,
    short* As, short* Bs, int tid, floatx4 acc[4][4])
{
  const int lane = tid & 63, w = tid >> 6;
  const int quad = lane >> 4, l16 = lane & 15;
  const int wt = (w >> 1)*64, wn = (w & 1)*64;
  const int srow = lane >> 2, skoff = (lane & 3)*8;
  const int r0 = w*32;
  bfu* ldsA0 = (bfu*)&As[(r0)*32];
  bfu* ldsA1 = (bfu*)&As[(r0+16)*32];
  bfu* ldsB0 = (bfu*)&Bs[(r0)*32];
  bfu* ldsB1 = (bfu*)&Bs[(r0+16)*32];
  const bfu* gA0 = Xb + (size_t)(r0 + srow)*K + skoff;
  const bfu* gA1 = Xb + (size_t)(r0 + 16 + srow)*K + skoff;
  const bfu* gB0 = Wb + (size_t)(r0 + srow)*K + skoff;
  const bfu* gB1 = Wb + (size_t)(r0 + 16 + srow)*K + skoff;

  for (int k0 = 0; k0 < K; k0 += 32){
    __syncthreads();
    gld16(gA0 + k0, ldsA0);
    gld16(gA1 + k0, ldsA1);
    gld16(gB0 + k0, ldsB0);
    gld16(gB1 + k0, ldsB1);
    __syncthreads();
    short8 af[4], bf[4];
#pragma unroll
    for (int i = 0; i < 4; i++) af[i] = *(short8*)&As[(wt + i*16 + l16)*32 + quad*8];
#pragma unroll
    for (int i = 0; i < 4; i++) bf[i] = *(short8*)&Bs[(wn + i*16 + l16)*32 + quad*8];
#pragma unroll
    for (int i = 0; i < 4; i++)
#pragma unroll
      for (int j = 0; j < 4; j++){
        if (TR) acc[i][j] = __builtin_amdgcn_mfma_f32_16x16x32_bf16(bf[i], af[j], acc[i][j], 0,0,0);
        else    acc[i][j] = __builtin_amdgcn_mfma_f32_16x16x32_bf16(af[i], bf[j], acc[i][j], 0,0,0);
      }
  }
}

// plain GEMM: OUT (B,T,M) = X (B,T,K) · W(M,K)^T + bias (+res) (gelu)
__global__ __launch_bounds__(256) void gemm128(
    const bfu* __restrict__ X, const bfu* __restrict__ W,
    const float* __restrict__ bias, bfu* __restrict__ OUT,
    const bfu* __restrict__ res1,
    int T, int M, int K, int gelu)
{
  __shared__ __align__(16) short As[128*32];
  __shared__ __align__(16) short Bs[128*32];
  const int b = blockIdx.z;
  const int t0 = blockIdx.x*128, m0 = blockIdx.y*128;
  const int tid = threadIdx.x, lane = tid & 63;
  const int quad = lane >> 4, l16 = lane & 15;
  const int w = tid >> 6, wt = (w >> 1)*64, wn = (w & 1)*64;

  floatx4 acc[4][4];
#pragma unroll
  for (int i = 0; i < 4; i++)
#pragma unroll
    for (int j = 0; j < 4; j++) acc[i][j] = (floatx4){0.f,0.f,0.f,0.f};

  mm_core<false>(X + ((size_t)b*T + t0)*K, W + (size_t)m0*K, K, As, Bs, tid, acc);

  size_t ob = (size_t)b*T;
#pragma unroll
  for (int ti = 0; ti < 4; ti++){
    int t = t0 + wt + ti*16 + quad*4;
#pragma unroll
    for (int mi = 0; mi < 4; mi++){
      int m = m0 + wn + mi*16 + l16;
      float bi = bias[m];
#pragma unroll
      for (int i = 0; i < 4; i++){
        size_t o = (ob + t + i)*(size_t)M + m;
        float v = acc[ti][mi][i] + bi;
        if (res1) v += bu2f(res1[o]);
        if (gelu) v = 0.5f*v*(1.f + erff(v*0.70710678f));
        OUT[o] = f2bu(v);
      }
    }
  }
}

// merged q/k/v GEMM; which==2 (V) stores transposed (B,M,T) via operand swap
struct QKV3 {
  const bfu* X[3]; const bfu* W[3]; const float* bias[3]; bfu* O[3];
};
__global__ __launch_bounds__(256) void qkv_gemm(QKV3 a, int T)
{
  __shared__ __align__(16) short As[128*32];
  __shared__ __align__(16) short Bs[128*32];
  const int z = blockIdx.z, b = z & 1, which = z >> 1;
  const int t0 = blockIdx.x*128, m0 = blockIdx.y*128;
  const int tid = threadIdx.x, lane = tid & 63;
  const int quad = lane >> 4, l16 = lane & 15;
  const int w = tid >> 6, wt = (w >> 1)*64, wn = (w & 1)*64;
  const bfu* Xb = a.X[which] + ((size_t)b*T + t0)*512;
  const bfu* Wb = a.W[which] + (size_t)m0*512;
  const float* bias = a.bias[which];
  bfu* O = a.O[which];

  floatx4 acc[4][4];
#pragma unroll
  for (int i = 0; i < 4; i++)
#pragma unroll
    for (int j = 0; j < 4; j++) acc[i][j] = (floatx4){0.f,0.f,0.f,0.f};

  if (which == 2){
    mm_core<true>(Xb, Wb, 512, As, Bs, tid, acc);
#pragma unroll
    for (int mi = 0; mi < 4; mi++){
      int m = m0 + wn + mi*16 + quad*4;
#pragma unroll
      for (int ti = 0; ti < 4; ti++){
        int t = t0 + wt + ti*16 + l16;
#pragma unroll
        for (int i = 0; i < 4; i++)
          O[((size_t)b*512 + m + i)*T + t] = f2bu(acc[mi][ti][i] + bias[m + i]);
      }
    }
  } else {
    mm_core<false>(Xb, Wb, 512, As, Bs, tid, acc);
    size_t ob = (size_t)b*T;
#pragma unroll
    for (int ti = 0; ti < 4; ti++){
      int t = t0 + wt + ti*16 + quad*4;
#pragma unroll
      for (int mi = 0; mi < 4; mi++){
        int m = m0 + wn + mi*16 + l16;
        float bi = bias[m];
#pragma unroll
        for (int i = 0; i < 4; i++)
          O[(ob + t + i)*512 + m] = f2bu(acc[ti][mi][i] + bi);
      }
    }
  }
}

// ---------------- flash attention: R7 dataflow, 32 q-rows/wave (2 Q fragments share K/V) ----------------
// grid (16 bh -> XCD pin, T/128, nsp). Q,K (B,T,512); V (B,512,T).
// S=mfma(A=Q,B=K): C row=q(quad*4+i), col=s(l16). P via per-wave LDS -> A-layout. Max-free softmax.
struct POP { bfu* p[4]; };
__global__ __launch_bounds__(256) void attn_kernel(
    const bfu* __restrict__ Q, const bfu* __restrict__ K,
    const bfu* __restrict__ V, POP po, float* __restrict__ lbuf,
    int T, int nsp)
{
  __shared__ __align__(16) short Ps[4][2][16*72];
  int bh = blockIdx.x, b = bh >> 3, h = bh & 7;
  int t0 = blockIdx.y*128;
  int sp = blockIdx.z, chunk = T/nsp, s_begin = sp*chunk;
  int tid = threadIdx.x, lane = tid & 63, w = tid >> 6;
  int quad = lane >> 4, l16 = lane & 15;
  int qbase = t0 + w*32;
  const bfu* Qb = Q + ((size_t)b*T)*512 + h*64;
  const bfu* Kb = K + ((size_t)b*T)*512 + h*64;
  const bfu* Vb = V + ((size_t)b*512 + h*64)*T;

  short8 a[2][2];
#pragma unroll
  for (int qt = 0; qt < 2; qt++){
    const bfu* qrow = Qb + (size_t)(qbase + qt*16 + l16)*512;
    a[qt][0] = *(const short8*)&qrow[quad*8];
    a[qt][1] = *(const short8*)&qrow[32 + quad*8];
  }

  floatx4 o[2][4];
#pragma unroll
  for (int qt = 0; qt < 2; qt++)
#pragma unroll
    for (int dn = 0; dn < 4; dn++) o[qt][dn] = (floatx4){0.f,0.f,0.f,0.f};
  float lsum[2][4] = {{0.f,0.f,0.f,0.f},{0.f,0.f,0.f,0.f}};
  const float C8 = 0.18033688f;   // 0.125 * log2(e); scores bounded (R7-verified), max-free safe

  for (int s0 = s_begin; s0 < s_begin + chunk; s0 += 64){
#pragma unroll
    for (int sn = 0; sn < 4; sn++){
      const bfu* krow = Kb + (size_t)(s0 + sn*16 + l16)*512;
      short8 k0 = *(const short8*)&krow[quad*8];
      short8 k1 = *(const short8*)&krow[32 + quad*8];
#pragma unroll
      for (int qt = 0; qt < 2; qt++){
        floatx4 acc = (floatx4){0.f,0.f,0.f,0.f};
        acc = __builtin_amdgcn_mfma_f32_16x16x32_bf16(a[qt][0], k0, acc, 0,0,0);
        acc = __builtin_amdgcn_mfma_f32_16x16x32_bf16(a[qt][1], k1, acc, 0,0,0);
#pragma unroll
        for (int i = 0; i < 4; i++){
          float p = exp2f(acc[i]*C8);
          lsum[qt][i] += p;
          Ps[w][qt][(quad*4 + i)*72 + sn*16 + l16] = (short)f2bu(p);
        }
      }
    }
    // V loads shared by both q-tiles
    short8 v0[4], v1[4];
#pragma unroll
    for (int dn = 0; dn < 4; dn++){
      const bfu* vrow = Vb + (size_t)(dn*16 + l16)*T + s0;
      v0[dn] = *(const short8*)&vrow[quad*8];
      v1[dn] = *(const short8*)&vrow[32 + quad*8];
    }
#pragma unroll
    for (int qt = 0; qt < 2; qt++){
      short8 pa0 = *(short8*)&Ps[w][qt][l16*72 + quad*8];
      short8 pa1 = *(short8*)&Ps[w][qt][l16*72 + 32 + quad*8];
#pragma unroll
      for (int dn = 0; dn < 4; dn++){
        o[qt][dn] = __builtin_amdgcn_mfma_f32_16x16x32_bf16(pa0, v0[dn], o[qt][dn], 0,0,0);
        o[qt][dn] = __builtin_amdgcn_mfma_f32_16x16x32_bf16(pa1, v1[dn], o[qt][dn], 0,0,0);
      }
    }
  }

  size_t lin0 = (size_t)sp * 1024 * T;   // sp region start (elems); regions are plane-packed
#pragma unroll
  for (int qt = 0; qt < 2; qt++){
    float linv[4];
#pragma unroll
    for (int i = 0; i < 4; i++){
      float rs = lsum[qt][i];
#pragma unroll
      for (int off = 1; off < 16; off <<= 1) rs += __shfl_xor(rs, off, 16);
      lsum[qt][i] = rs;
      linv[i] = 1.f / rs;
    }
#pragma unroll
    for (int dn = 0; dn < 4; dn++)
#pragma unroll
      for (int i = 0; i < 4; i++){
        size_t lin = lin0 + ((size_t)b*T + qbase + qt*16 + quad*4 + i)*512 + h*64 + dn*16 + l16;
        po.p[lin >> 21][lin & 2097151] = f2bu(o[qt][dn][i] * linv[i]);
      }
    if (l16 == 0){
#pragma unroll
      for (int i = 0; i < 4; i++)
        lbuf[(size_t)(sp*16 + bh)*T + qbase + qt*16 + quad*4 + i] = lsum[qt][i];
    }
  }
}

// ---------------- combine split partials (all (B,T,C) inside each sp region) ----------------
__global__ __launch_bounds__(256) void attn_combine_kernel(
    POP po, const float* __restrict__ lbuf, bfu* __restrict__ attout, int T, int nsp)
{
  int idx = blockIdx.x*256 + threadIdx.x;
  if (idx >= 2*T*512) return;
  int c = idx & 511, tc = idx >> 9, t = tc % T, b = tc / T;
  int bh = b*8 + (c >> 6);
  float wsum = 0.f, acc = 0.f;
  for (int sp = 0; sp < nsp; sp++){
    float l = lbuf[(size_t)(sp*16 + bh)*T + t];
    size_t lin = (size_t)sp*1024*T + (size_t)idx;
    wsum += l;
    acc  += l * bu2f(po.p[lin >> 21][lin & 2097151]);
  }
  attout[idx] = f2bu(acc / wsum);
}

// ---------------- GroupNorm partials / fused finalize+apply, (B,T,C) ----------------
__global__ __launch_bounds__(256) void gnA(
    const bfu* __restrict__ X, float* __restrict__ pgn, int T)
{
  __shared__ float L1[4][64], L2[4][64];
  int tl = threadIdx.x & 63, wv = threadIdx.x >> 6;
  int t0 = blockIdx.x*64, cb = blockIdx.y, b = blockIdx.z;
  int c0 = cb*64;
  float s = 0.f, ss = 0.f;
#pragma unroll 4
  for (int r = 0; r < 16; r++){
    float v = bu2f(X[((size_t)b*T + t0 + wv*16 + r)*512 + c0 + tl]);
    s += v; ss += v*v;
  }
  L1[wv][tl] = s; L2[wv][tl] = ss;
  __syncthreads();
  if (wv == 0){
    float cs  = L1[0][tl]+L1[1][tl]+L1[2][tl]+L1[3][tl];
    float css = L2[0][tl]+L2[1][tl]+L2[2][tl]+L2[3][tl];
#pragma unroll
    for (int off = 1; off < 32; off <<= 1){
      cs  += __shfl_xor(cs,  off, 32);
      css += __shfl_xor(css, off, 32);
    }
    if (tl == 0 || tl == 32){
      int g = cb*2 + (tl >> 5);
      float* pp = pgn + (((size_t)b*16 + g)*32 + blockIdx.x)*2;
      pp[0] = cs; pp[1] = css;
    }
  }
}

__global__ __launch_bounds__(256) void gnapply_kernel(
    const bfu* __restrict__ X, const float* __restrict__ pgn,
    const float* __restrict__ w, const float* __restrict__ bb,
    bfu* __restrict__ OUT, int T, int nch)
{
  __shared__ float smu[8], srs[8];
  int idx = blockIdx.x*256 + threadIdx.x;
  int c = idx & 511, b = (idx >> 9) / T;
  int tid = threadIdx.x;
  if (tid < 8){
    int c0 = (blockIdx.x*256) & 511;
    int g = (c0 >> 5) + tid;
    float S = 0.f, SS = 0.f;
    for (int ch = 0; ch < nch; ch++){
      const float* pp = pgn + (((size_t)b*16 + g)*32 + ch)*2;
      S += pp[0]; SS += pp[1];
    }
    float n = 32.f*(float)T;
    float mu = S/n, var = SS/n - mu*mu;
    smu[tid] = mu; srs[tid] = rsqrtf(var + 1e-5f);
  }
  __syncthreads();
  if (idx >= 2*T*512) return;
  int gl = (c >> 5) & 7;
  float mu = smu[gl], rs = srs[gl];
  OUT[idx] = f2bu((bu2f(X[idx]) - mu)*rs*w[c] + bb[c]);
}

// ---------------- final: (B,T,C) bf16 -> d_out (B,C,T) fp32 ----------------
__global__ __launch_bounds__(256) void trans_out(
    const bfu* __restrict__ IN, float* __restrict__ OUT, int T)
{
  __shared__ float Ls[64*65];
  int tl = threadIdx.x & 63, wv = threadIdx.x >> 6;
  int t0 = blockIdx.x*64, c0 = blockIdx.y*64, b = blockIdx.z;
#pragma unroll 4
  for (int r = 0; r < 16; r++){
    int t = t0 + wv*16 + r;
    Ls[tl*65 + wv*16 + r] = bu2f(IN[((size_t)b*T + t)*512 + c0 + tl]);
  }
  __syncthreads();
#pragma unroll 4
  for (int r = 0; r < 16; r++){
    int c = c0 + wv*16 + r;
    OUT[((size_t)b*512 + c)*T + t0 + tl] = Ls[(wv*16+r)*65 + tl];
  }
}

// ---------------- launch ----------------
extern "C" void kernel_launch(void* const* d_in, const int* in_sizes, int n_in,
                              void* d_out, int out_size, void* d_ws, size_t ws_size,
                              hipStream_t stream)
{
  (void)in_sizes; (void)n_in; (void)out_size; (void)ws_size;
  const int B = 2;
  const float* xs_in[3] = {(const float*)d_in[0], (const float*)d_in[1], (const float*)d_in[2]};
  const int Ts[3] = {512, 1024, 2048};
  const float* ln_w   = (const float*)d_in[6];
  const float* ln_b   = (const float*)d_in[7];
  const float* gn_w   = (const float*)d_in[8];
  const float* gn_b   = (const float*)d_in[9];
  const float* psi_w  = (const float*)d_in[10];
  const float* psi_b  = (const float*)d_in[11];
  const float* fc_w   = (const float*)d_in[12];
  const float* fc_b   = (const float*)d_in[13];
  const float* convw_w = (const float*)d_in[14];
  const float* convw_b = (const float*)d_in[15];
  const float* ckw_ws[3] = {(const float*)d_in[16], (const float*)d_in[18], (const float*)d_in[20]};
  const float* ckw_bs[3] = {(const float*)d_in[17], (const float*)d_in[19], (const float*)d_in[21]};
  const int   ckw_ks[3] = {1, 3, 5};
  const float* gfc_w  = (const float*)d_in[22];
  const float* gfc_b  = (const float*)d_in[23];
  const float* ca_dw  = (const float*)d_in[24];
  const float* ca_nw  = (const float*)d_in[25];
  const float* ca_nb  = (const float*)d_in[26];
  const float* qkv_w  = (const float*)d_in[27];
  const float* qkv_b  = (const float*)d_in[28];
  const float* proj_w = (const float*)d_in[29];
  const float* proj_b = (const float*)d_in[30];
  const float* mlp1_w = (const float*)d_in[31];
  const float* mlp1_b = (const float*)d_in[32];
  const float* mlp2_w = (const float*)d_in[33];
  const float* mlp2_b = (const float*)d_in[34];

  char* ws = (char*)d_ws;
  const size_t P = (size_t)2*2048*512*2;   // 4 MB plane
  // slot map:
  // s0: out_cln -> [clnC, prepqkv, resadd] ; then po ; then hidden[0]
  // s1: x_btc -> resadd(in-place) ; proj res ; hidden[1]
  // s2..s4: qpre/kpre/vpre -> qkv ; po ; hidden[2,3]/mlp2out
  // s5..s7: vbuf/qbuf/kbuf -> attn ; gnout/attout/resb
  bfu* out_cln = (bfu*)(ws + 0*P);
  bfu* x_btc   = (bfu*)(ws + 1*P);
  bfu* qpre    = (bfu*)(ws + 2*P);
  bfu* kpre    = (bfu*)(ws + 3*P);
  bfu* vpre    = (bfu*)(ws + 4*P);
  bfu* vbuf    = (bfu*)(ws + 5*P);
  bfu* qbuf    = (bfu*)(ws + 6*P);
  bfu* kbuf    = (bfu*)(ws + 7*P);
  bfu* attout  = qbuf;
  bfu* resb    = kbuf;
  bfu* gnout   = vbuf;
  bfu* hidden  = out_cln;
  bfu* mlp2out = vpre;
  bfu* wqkvB  = (bfu*)(ws + 8*P);
  bfu* wprojB = wqkvB + 3*512*512;
  bfu* wm1B   = wprojB + 512*512;
  bfu* wm2B   = wm1B + 2048*512;
  float* part  = (float*)((char*)(wm2B + 512*2048));  // 65536 f
  float* pp    = part + 65536;                        // 32768 f
  float* phi   = pp + 32768;                          // 1024 f
  float* lbuf  = phi + 1024;                          // 131072 f
  float* pgn   = lbuf + 131072;                       // 2048 f

  F2B fa;
  fa.s[0] = qkv_w;  fa.d[0] = wqkvB;  fa.n[0] = 3*512*512;
  fa.s[1] = proj_w; fa.d[1] = wprojB; fa.n[1] = 512*512;
  fa.s[2] = mlp1_w; fa.d[2] = wm1B;   fa.n[2] = 2048*512;
  fa.s[3] = mlp2_w; fa.d[3] = wm2B;   fa.n[3] = 512*2048;
  f2b_all<<<dim3(4096, 4), 256, 0, stream>>>(fa);

  size_t out_off = 0;
  for (int bi = 0; bi < 3; bi++){
    int T = Ts[bi];
    int nsp = (T == 2048) ? 4 : 8;      // attn blocks: 1024/1024/512; po <= 4 plane-slots
    int nch = T / 64;
    const float* x = xs_in[bi];
    float* outp = (float*)d_out + out_off;
    int nelem = B*512*T;
    dim3 eb((nelem + 255)/256);

    clnA_f32<<<dim3(T/64, 8, B), 256, 0, stream>>>(x, part, T);
    clnC_trans<<<dim3(T/64, 8, B), 256, 0, stream>>>(x, part, ln_w, ln_b, out_cln, x_btc, pp, T);
    phiB<<<4, 256, 0, stream>>>(pp, gfc_w, gfc_b, phi, T, nch);

    prepqkv<<<B*T, 512, 0, stream>>>(out_cln, phi, psi_w, psi_b,
        convw_w + bi*512*3, convw_b + bi*512, ckw_ws[bi], ckw_bs[bi], ckw_ks[bi],
        fc_w, fc_b, ca_dw, ca_nw, ca_nb, qpre, kpre, vpre, T);

    QKV3 qa;
    qa.X[0] = qpre;  qa.X[1] = kpre;  qa.X[2] = vpre;
    qa.W[0] = wqkvB; qa.W[1] = wqkvB + 262144; qa.W[2] = wqkvB + 524288;
    qa.bias[0] = qkv_b; qa.bias[1] = qkv_b + 512; qa.bias[2] = qkv_b + 1024;
    qa.O[0] = qbuf; qa.O[1] = kbuf; qa.O[2] = vbuf;
    qkv_gemm<<<dim3(T/128, 4, 6), 256, 0, stream>>>(qa, T);

    resadd_kernel<<<eb, 256, 0, stream>>>(out_cln, x_btc, nelem);

    POP pos; pos.p[0] = out_cln; pos.p[1] = qpre; pos.p[2] = kpre; pos.p[3] = vpre;
    attn_kernel<<<dim3(16, T/128, nsp), 256, 0, stream>>>(qbuf, kbuf, vbuf, pos, lbuf, T, nsp);
    attn_combine_kernel<<<eb, 256, 0, stream>>>(pos, lbuf, attout, T, nsp);

    gemm128<<<dim3(T/128, 4, B), 256, 0, stream>>>(attout, wprojB, proj_b, resb, x_btc, T, 512, 512, 0);

    gnA<<<dim3(T/64, 8, B), 256, 0, stream>>>(resb, pgn, T);
    gnapply_kernel<<<eb, 256, 0, stream>>>(resb, pgn, gn_w, gn_b, gnout, T, nch);

    gemm128<<<dim3(T/128, 16, B), 256, 0, stream>>>(gnout, wm1B, mlp1_b, hidden, nullptr, T, 2048, 512, 1);
    gemm128<<<dim3(T/128, 4, B), 256, 0, stream>>>(hidden, wm2B, mlp2_b, mlp2out, resb, T, 512, 2048, 0);

    trans_out<<<dim3(T/64, 8, B), 256, 0, stream>>>(mlp2out, outp, T);

    out_off += (size_t)nelem;
  }
}